// Round 1
// baseline (163.474 us; speedup 1.0000x reference)
//
#include <hip/hip_runtime.h>
#include <hip/hip_bf16.h>
#include <stdint.h>

#define BB 64
#define NN 196
#define D1c 512
#define D2c 2048
#define HHc 512
#define MM (BB*NN)   // 12544

typedef __attribute__((ext_vector_type(8))) short bf16x8;
typedef __attribute__((ext_vector_type(4))) float f32x4;

__device__ inline ushort f2bf(float f){
  uint32_t u = __float_as_uint(f);
  u += 0x7fff + ((u >> 16) & 1);   // RNE
  return (ushort)(u >> 16);
}
__device__ inline uint32_t pack2(float a, float b){
  return (uint32_t)f2bf(a) | ((uint32_t)f2bf(b) << 16);
}

// ---- W2 [2048][512] f32  ->  w2t [512][2048] bf16 (transposed) ----
__global__ __launch_bounds__(256) void w2t_kernel(const float* __restrict__ W2,
                                                  ushort* __restrict__ w2t){
  __shared__ float tile[64][65];
  const int kt = blockIdx.x;           // 32 tiles of 64 k
  const int ht = blockIdx.y;           // 8 tiles of 64 h
  const int t = threadIdx.x;
  const int tr = t >> 4;               // 0..15
  const int tc = (t & 15) * 4;         // 0..60
  #pragma unroll
  for (int p = 0; p < 4; ++p){
    int k = p*16 + tr;
    float4 v = *(const float4*)(W2 + (size_t)(kt*64 + k)*HHc + ht*64 + tc);
    tile[k][tc] = v.x; tile[k][tc+1] = v.y; tile[k][tc+2] = v.z; tile[k][tc+3] = v.w;
  }
  __syncthreads();
  #pragma unroll
  for (int p = 0; p < 4; ++p){
    int h = p*16 + tr;
    ushort4 o;
    o.x = f2bf(tile[tc  ][h]);
    o.y = f2bf(tile[tc+1][h]);
    o.z = f2bf(tile[tc+2][h]);
    o.w = f2bf(tile[tc+3][h]);
    *(ushort4*)(w2t + (size_t)(ht*64 + h)*D2c + kt*64 + tc) = o;
  }
}

// ---- enc1 = input1 @ W1 + b1   [64][512] f32 ----
__global__ __launch_bounds__(512) void enc1_kernel(const float* __restrict__ in1,
                                                   const float* __restrict__ W1,
                                                   const float* __restrict__ b1,
                                                   float* __restrict__ enc1){
  __shared__ float s1[D1c];
  const int b = blockIdx.x;
  const int h = threadIdx.x;
  s1[h] = in1[b*D1c + h];
  __syncthreads();
  float acc = b1[h];
  #pragma unroll 8
  for (int d = 0; d < D1c; ++d)
    acc += s1[d] * W1[(size_t)d*HHc + h];
  enc1[b*HHc + h] = acc;
}

// ---- fused scores GEMM:  scores[m] += sum_h relu(A@W2 + b2 + enc1) * Wf ----
// A = input2 viewed as [12544][2048] f32 (converted to bf16 on the fly)
__global__ __launch_bounds__(256,2) void score_gemm(
    const float*  __restrict__ in2,
    const ushort* __restrict__ w2t,     // [512][2048] bf16
    const float*  __restrict__ b2,
    const float*  __restrict__ wf,
    const float*  __restrict__ enc1,    // [64][512]
    float*        __restrict__ scores)  // [12544], pre-zeroed
{
  __shared__ ushort As[128*64];   // [row][k] bf16, 16B-chunk XOR swizzle c^=(row&7)
  __shared__ ushort Bs[128*64];   // [h][k] bf16, same swizzle

  const int t    = threadIdx.x;
  const int m0   = blockIdx.x * 128;
  const int h0   = blockIdx.y * 128;
  const int wave = t >> 6, lane = t & 63;
  const int wm   = wave >> 1, wh = wave & 1;    // 2x2 wave grid
  const int l15  = lane & 15, l4 = lane >> 4;

  // A staging map: thread -> (row = t>>1, k-half = (t&1)*32)
  const int ar = t >> 1;
  const int ak = (t & 1) * 32;
  const float* aSrc0 = in2 + (size_t)(m0 + ar)*D2c + ak;
  ushort* aDst = As + ar*64;

  float b2v[4], wfv[4];
  #pragma unroll
  for (int hf = 0; hf < 4; ++hf){
    int hc = h0 + wh*64 + hf*16 + l15;
    b2v[hf] = b2[hc]; wfv[hf] = wf[hc];
  }

  f32x4 acc[4][4];
  #pragma unroll
  for (int i = 0; i < 4; ++i)
    #pragma unroll
    for (int j = 0; j < 4; ++j) acc[i][j] = (f32x4)0.f;

  for (int kt = 0; kt < 32; ++kt){
    // --- stage A (f32 -> bf16, swizzled ds_write) ---
    const float* aSrc = aSrc0 + kt*64;
    #pragma unroll
    for (int j = 0; j < 8; ++j){
      float4 v = *(const float4*)(aSrc + j*4);
      int kk2 = ak + j*4;
      int c = kk2 >> 3, half = (kk2 >> 2) & 1;
      uint2 pk; pk.x = pack2(v.x, v.y); pk.y = pack2(v.z, v.w);
      *(uint2*)(aDst + ((c ^ (ar & 7)) << 3) + half*4) = pk;
    }
    // --- stage Bt (global_load_lds 16B, pre-swizzled global source) ---
    #pragma unroll
    for (int i = 0; i < 4; ++i){
      int row = (wave*4 + i)*8 + (lane >> 3);
      int c   = (lane & 7) ^ (lane >> 3);       // (c ^ (row&7))
      const ushort* src = w2t + (size_t)(h0 + row)*D2c + kt*64 + (c << 3);
      __builtin_amdgcn_global_load_lds(
          (const __attribute__((address_space(1))) uint32_t*)src,
          (__attribute__((address_space(3))) uint32_t*)(Bs + (wave*4 + i)*512),
          16, 0, 0);
    }
    __syncthreads();
    // --- compute ---
    #pragma unroll
    for (int kk = 0; kk < 2; ++kk){
      bf16x8 af[4], bfr[4];
      #pragma unroll
      for (int mf = 0; mf < 4; ++mf){
        int row = wm*64 + mf*16 + l15;
        int c   = kk*4 + l4;
        af[mf] = *(const bf16x8*)(As + row*64 + ((c ^ (row & 7)) << 3));
      }
      #pragma unroll
      for (int hf = 0; hf < 4; ++hf){
        int row = wh*64 + hf*16 + l15;
        int c   = kk*4 + l4;
        bfr[hf] = *(const bf16x8*)(Bs + row*64 + ((c ^ (row & 7)) << 3));
      }
      #pragma unroll
      for (int mf = 0; mf < 4; ++mf)
        #pragma unroll
        for (int hf = 0; hf < 4; ++hf)
          acc[mf][hf] = __builtin_amdgcn_mfma_f32_16x16x32_bf16(
              af[mf], bfr[hf], acc[mf][hf], 0, 0, 0);
    }
    __syncthreads();
  }

  // --- epilogue: relu + Wf reduce over this block's 128 h, atomic into scores ---
  #pragma unroll
  for (int mf = 0; mf < 4; ++mf){
    #pragma unroll
    for (int r = 0; r < 4; ++r){
      int m = m0 + wm*64 + mf*16 + l4*4 + r;   // C/D: row=(lane>>4)*4+reg
      int b = m / NN;
      const float* e1 = enc1 + b*HHc + h0 + wh*64 + l15;
      float s = 0.f;
      #pragma unroll
      for (int hf = 0; hf < 4; ++hf){
        float v = acc[mf][hf][r] + b2v[hf] + e1[hf*16];
        s += fmaxf(v, 0.f) * wfv[hf];
      }
      s += __shfl_xor(s, 1); s += __shfl_xor(s, 2);
      s += __shfl_xor(s, 4); s += __shfl_xor(s, 8);
      if (l15 == 0) atomicAdd(&scores[m], s);
    }
  }
}

// ---- softmax over N=196 per batch ----
__global__ __launch_bounds__(64) void softmax_kernel(const float* __restrict__ scores,
                                                     float* __restrict__ alpha){
  const int b = blockIdx.x, t = threadIdx.x;
  const float* s = scores + b*NN;
  float x[4]; float mx = -1e30f;
  #pragma unroll
  for (int i = 0; i < 4; ++i){
    int n = t + i*64;
    x[i] = (n < NN) ? s[n] : -1e30f;
    mx = fmaxf(mx, x[i]);
  }
  #pragma unroll
  for (int o = 1; o < 64; o <<= 1) mx = fmaxf(mx, __shfl_xor(mx, o));
  float sum = 0.f;
  #pragma unroll
  for (int i = 0; i < 4; ++i){
    int n = t + i*64;
    float e = (n < NN) ? __expf(x[i] - mx) : 0.f;
    x[i] = e; sum += e;
  }
  #pragma unroll
  for (int o = 1; o < 64; o <<= 1) sum += __shfl_xor(sum, o);
  float inv = 1.f / sum;
  #pragma unroll
  for (int i = 0; i < 4; ++i){
    int n = t + i*64;
    if (n < NN) alpha[b*NN + n] = x[i] * inv;
  }
}

// ---- att[b,d] = sum_n input2[b,n,d] * alpha[b,n] ----
__global__ __launch_bounds__(256) void att_kernel(const float* __restrict__ in2,
                                                  const float* __restrict__ alpha,
                                                  float* __restrict__ att){
  __shared__ float sal[NN];
  const int b = blockIdx.y;
  const int t = threadIdx.x;
  if (t < NN) sal[t] = alpha[b*NN + t];
  __syncthreads();
  const int d = blockIdx.x*1024 + t*4;
  const float* src = in2 + (size_t)b*NN*D2c + d;
  float4 acc = make_float4(0.f, 0.f, 0.f, 0.f);
  #pragma unroll 4
  for (int n = 0; n < NN; ++n){
    float4 v = *(const float4*)(src + (size_t)n*D2c);
    float a = sal[n];
    acc.x += v.x*a; acc.y += v.y*a; acc.z += v.z*a; acc.w += v.w*a;
  }
  *(float4*)(att + (size_t)b*D2c + d) = acc;
}

extern "C" void kernel_launch(void* const* d_in, const int* in_sizes, int n_in,
                              void* d_out, int out_size, void* d_ws, size_t ws_size,
                              hipStream_t stream){
  (void)in_sizes; (void)n_in; (void)out_size; (void)ws_size;
  const float* input1 = (const float*)d_in[0];
  const float* input2 = (const float*)d_in[1];
  const float* W1     = (const float*)d_in[2];
  const float* b1     = (const float*)d_in[3];
  const float* W2     = (const float*)d_in[4];
  const float* b2     = (const float*)d_in[5];
  const float* Wf     = (const float*)d_in[6];
  // d_in[7] = bf : softmax shift-invariant, provably unused.

  float* out   = (float*)d_out;
  float* att   = out;              // [64][2048]
  float* alpha = out + BB*D2c;     // [64][196]

  char*   ws     = (char*)d_ws;
  ushort* w2t    = (ushort*)ws;                              // 2 MiB
  float*  enc1   = (float*)(ws + 2*1024*1024);               // 128 KiB
  float*  scores = (float*)(ws + 2*1024*1024 + 131072);      // 50 KiB

  hipMemsetAsync(scores, 0, MM*sizeof(float), stream);
  w2t_kernel<<<dim3(32, 8), 256, 0, stream>>>(W2, w2t);
  enc1_kernel<<<dim3(BB), 512, 0, stream>>>(input1, W1, b1, enc1);
  score_gemm<<<dim3(98, 4), 256, 0, stream>>>(input2, w2t, b2, Wf, enc1, scores);
  softmax_kernel<<<dim3(BB), 64, 0, stream>>>(scores, alpha);
  att_kernel<<<dim3(2, BB), 256, 0, stream>>>(input2, alpha, att);
}

// Round 2
// 148.177 us; speedup vs baseline: 1.1032x; 1.1032x over previous
//
#include <hip/hip_runtime.h>
#include <hip/hip_bf16.h>
#include <stdint.h>

#define BB 64
#define NN 196
#define D1c 512
#define D2c 2048
#define HHc 512
#define MM (BB*NN)   // 12544

typedef __attribute__((ext_vector_type(8))) short bf16x8;
typedef __attribute__((ext_vector_type(4))) float f32x4;

__device__ inline ushort f2bf(float f){
  uint32_t u = __float_as_uint(f);
  u += 0x7fff + ((u >> 16) & 1);   // RNE
  return (ushort)(u >> 16);
}
__device__ inline uint32_t pack2(float a, float b){
  return (uint32_t)f2bf(a) | ((uint32_t)f2bf(b) << 16);
}

// ---- W2 [2048][512] f32  ->  w2t [512][2048] bf16 (transposed) ----
__global__ __launch_bounds__(256) void w2t_kernel(const float* __restrict__ W2,
                                                  ushort* __restrict__ w2t){
  __shared__ float tile[64][65];
  const int kt = blockIdx.x;           // 32 tiles of 64 k
  const int ht = blockIdx.y;           // 8 tiles of 64 h
  const int t = threadIdx.x;
  const int tr = t >> 4;               // 0..15
  const int tc = (t & 15) * 4;         // 0..60
  #pragma unroll
  for (int p = 0; p < 4; ++p){
    int k = p*16 + tr;
    float4 v = *(const float4*)(W2 + (size_t)(kt*64 + k)*HHc + ht*64 + tc);
    tile[k][tc] = v.x; tile[k][tc+1] = v.y; tile[k][tc+2] = v.z; tile[k][tc+3] = v.w;
  }
  __syncthreads();
  #pragma unroll
  for (int p = 0; p < 4; ++p){
    int h = p*16 + tr;
    ushort4 o;
    o.x = f2bf(tile[tc  ][h]);
    o.y = f2bf(tile[tc+1][h]);
    o.z = f2bf(tile[tc+2][h]);
    o.w = f2bf(tile[tc+3][h]);
    *(ushort4*)(w2t + (size_t)(ht*64 + h)*D2c + kt*64 + tc) = o;
  }
}

// ---- enc1 = input1 @ W1 + b1   [64][512] f32 ----
__global__ __launch_bounds__(128) void enc1_kernel(const float* __restrict__ in1,
                                                   const float* __restrict__ W1,
                                                   const float* __restrict__ b1,
                                                   float* __restrict__ enc1){
  __shared__ float s1[D1c];
  const int b = blockIdx.x;
  const int ht = blockIdx.y;
  const int t = threadIdx.x;
  ((float4*)s1)[t] = ((const float4*)(in1 + (size_t)b*D1c))[t];
  __syncthreads();
  const int h = ht*128 + t;
  float acc = b1[h];
  #pragma unroll 8
  for (int d = 0; d < D1c; ++d)
    acc += s1[d] * W1[(size_t)d*HHc + h];
  enc1[b*HHc + h] = acc;
}

// ---- fused scores GEMM:  scores[m] += sum_h relu(A@W2 + b2 + enc1) * Wf ----
// A = input2 viewed as [12544][2048] f32 (converted to bf16 on the fly)
// tile: 64 m x 128 h, BK=64, 4 waves (2x2), 2-phase double-buffered pipeline
__global__ __launch_bounds__(256,3) void score_gemm(
    const float*  __restrict__ in2,
    const ushort* __restrict__ w2t,     // [512][2048] bf16
    const float*  __restrict__ b2,
    const float*  __restrict__ wf,
    const float*  __restrict__ enc1,    // [64][512]
    float*        __restrict__ scores)  // [12544], pre-zeroed
{
  __shared__ ushort As[2][64*64];    // [row][k] bf16, 16B-chunk XOR swizzle c^=(row&7)
  __shared__ ushort Bs[2][128*64];   // [h][k] bf16, same swizzle

  const int t    = threadIdx.x;
  const int h0   = blockIdx.x * 128;   // 4 h-tiles  (fast grid dim -> L3 panel reuse)
  const int m0   = blockIdx.y * 64;    // 196 m-tiles
  const int wave = t >> 6, lane = t & 63;
  const int wm   = wave >> 1, wh = wave & 1;    // 2x2 wave grid, wave tile 32m x 64h
  const int l15  = lane & 15, l4 = lane >> 4;

  // A staging map: thread t -> rows (t>>4)+j*16 (j=0..3), k-col (t&15)*4 (one float4)
  const int arow  = t >> 4;            // 0..15
  const int acol  = (t & 15) * 4;      // 0..60
  const float* aBase = in2 + (size_t)(m0 + arow)*D2c + acol;
  const int ac    = acol >> 3;         // 16B chunk 0..7
  const int ahalf = (acol >> 2) & 1;

  // B staging map (global_load_lds, 16B, pre-swizzled global source)
  const int bgrp = wave * 4;           // 4 glds per wave
  const int bl_r = lane >> 3;          // row-within-8-group
  const int bl_c = (lane & 7) ^ bl_r;  // pre-swizzled chunk

  float b2v[4], wfv[4];
  #pragma unroll
  for (int hf = 0; hf < 4; ++hf){
    int hc = h0 + wh*64 + hf*16 + l15;
    b2v[hf] = b2[hc]; wfv[hf] = wf[hc];
  }

  f32x4 acc[2][4];
  #pragma unroll
  for (int i = 0; i < 2; ++i)
    #pragma unroll
    for (int j = 0; j < 4; ++j) acc[i][j] = (f32x4)0.f;

  float4 aReg[4];

#define A_LOAD(kt)                                                          \
  { _Pragma("unroll")                                                       \
    for (int j = 0; j < 4; ++j)                                             \
      aReg[j] = *(const float4*)(aBase + (size_t)(j*16)*D2c + (kt)*64); }

#define A_WRITE(buf)                                                        \
  { _Pragma("unroll")                                                       \
    for (int j = 0; j < 4; ++j){                                            \
      int r = arow + j*16;                                                  \
      uint2 pk; pk.x = pack2(aReg[j].x, aReg[j].y);                         \
      pk.y = pack2(aReg[j].z, aReg[j].w);                                   \
      *(uint2*)(As[buf] + r*64 + ((ac ^ (r & 7)) << 3) + ahalf*4) = pk; } }

#define B_GLDS(kt, buf)                                                     \
  { _Pragma("unroll")                                                       \
    for (int i = 0; i < 4; ++i){                                            \
      int row = (bgrp + i)*8 + bl_r;                                        \
      const ushort* src = w2t + (size_t)(h0 + row)*D2c + (kt)*64 + (bl_c<<3); \
      __builtin_amdgcn_global_load_lds(                                     \
          (const __attribute__((address_space(1))) uint32_t*)src,           \
          (__attribute__((address_space(3))) uint32_t*)(Bs[buf] + (bgrp+i)*512), \
          16, 0, 0); } }

#define COMPUTE(buf)                                                        \
  { _Pragma("unroll")                                                       \
    for (int kk = 0; kk < 2; ++kk){                                         \
      bf16x8 af[2], bfr[4];                                                 \
      _Pragma("unroll")                                                     \
      for (int mf = 0; mf < 2; ++mf){                                       \
        int r = wm*32 + mf*16 + l15;                                        \
        int c = kk*4 + l4;                                                  \
        af[mf] = *(const bf16x8*)(As[buf] + r*64 + ((c ^ (r & 7)) << 3)); } \
      _Pragma("unroll")                                                     \
      for (int hf = 0; hf < 4; ++hf){                                       \
        int r = wh*64 + hf*16 + l15;                                        \
        int c = kk*4 + l4;                                                  \
        bfr[hf] = *(const bf16x8*)(Bs[buf] + r*64 + ((c ^ (r & 7)) << 3)); }\
      _Pragma("unroll")                                                     \
      for (int mf = 0; mf < 2; ++mf)                                        \
        _Pragma("unroll")                                                   \
        for (int hf = 0; hf < 4; ++hf)                                      \
          acc[mf][hf] = __builtin_amdgcn_mfma_f32_16x16x32_bf16(            \
              af[mf], bfr[hf], acc[mf][hf], 0, 0, 0); } }

  // prologue: stage kt=0 into buffer 0
  A_LOAD(0);
  B_GLDS(0, 0);
  A_WRITE(0);
  __syncthreads();

  int cur = 0;
  for (int kt = 0; kt < 31; ++kt){
    A_LOAD(kt + 1);            // issue next A (f32 -> regs)
    B_GLDS(kt + 1, cur ^ 1);   // issue next B (HBM -> LDS direct)
    COMPUTE(cur);              // MFMA on current buffers (hides the loads)
    A_WRITE(cur ^ 1);          // convert + swizzled ds_write (waits A vmcnt only)
    __syncthreads();           // drains glds + ds_write
    cur ^= 1;
  }
  COMPUTE(cur);

  // epilogue: relu + Wf partial over this block's 128 h, atomic into scores
  #pragma unroll
  for (int mf = 0; mf < 2; ++mf){
    #pragma unroll
    for (int r = 0; r < 4; ++r){
      int m = m0 + wm*32 + mf*16 + l4*4 + r;   // C/D: row=(lane>>4)*4+reg, col=lane&15
      int b = m / NN;
      const float* e1 = enc1 + (size_t)b*HHc + h0 + wh*64 + l15;
      float s = 0.f;
      #pragma unroll
      for (int hf = 0; hf < 4; ++hf){
        float v = acc[mf][hf][r] + b2v[hf] + e1[hf*16];
        s += fmaxf(v, 0.f) * wfv[hf];
      }
      s += __shfl_xor(s, 1); s += __shfl_xor(s, 2);
      s += __shfl_xor(s, 4); s += __shfl_xor(s, 8);
      if (l15 == 0) atomicAdd(&scores[m], s);
    }
  }
#undef A_LOAD
#undef A_WRITE
#undef B_GLDS
#undef COMPUTE
}

// ---- softmax over N=196 per batch ----
__global__ __launch_bounds__(64) void softmax_kernel(const float* __restrict__ scores,
                                                     float* __restrict__ alpha){
  const int b = blockIdx.x, t = threadIdx.x;
  const float* s = scores + b*NN;
  float x[4]; float mx = -1e30f;
  #pragma unroll
  for (int i = 0; i < 4; ++i){
    int n = t + i*64;
    x[i] = (n < NN) ? s[n] : -1e30f;
    mx = fmaxf(mx, x[i]);
  }
  #pragma unroll
  for (int o = 1; o < 64; o <<= 1) mx = fmaxf(mx, __shfl_xor(mx, o));
  float sum = 0.f;
  #pragma unroll
  for (int i = 0; i < 4; ++i){
    int n = t + i*64;
    float e = (n < NN) ? __expf(x[i] - mx) : 0.f;
    x[i] = e; sum += e;
  }
  #pragma unroll
  for (int o = 1; o < 64; o <<= 1) sum += __shfl_xor(sum, o);
  float inv = 1.f / sum;
  #pragma unroll
  for (int i = 0; i < 4; ++i){
    int n = t + i*64;
    if (n < NN) alpha[b*NN + n] = x[i] * inv;
  }
}

// ---- att[b,d] = sum_n input2[b,n,d] * alpha[b,n] ----
// grid (8, 64): block = (d-slice of 256, batch). 512 blocks, no atomics.
__global__ __launch_bounds__(256) void att_kernel(const float* __restrict__ in2,
                                                  const float* __restrict__ alpha,
                                                  float* __restrict__ att){
  __shared__ float sal[NN];
  const int b = blockIdx.y;
  const int t = threadIdx.x;
  if (t < NN) sal[t] = alpha[b*NN + t];
  __syncthreads();
  const int d = blockIdx.x*256 + t;
  const float* src = in2 + (size_t)b*NN*D2c + d;
  float acc = 0.f;
  #pragma unroll 7
  for (int n = 0; n < NN; ++n)
    acc += src[(size_t)n*D2c] * sal[n];
  att[(size_t)b*D2c + d] = acc;
}

extern "C" void kernel_launch(void* const* d_in, const int* in_sizes, int n_in,
                              void* d_out, int out_size, void* d_ws, size_t ws_size,
                              hipStream_t stream){
  (void)in_sizes; (void)n_in; (void)out_size; (void)ws_size;
  const float* input1 = (const float*)d_in[0];
  const float* input2 = (const float*)d_in[1];
  const float* W1     = (const float*)d_in[2];
  const float* b1     = (const float*)d_in[3];
  const float* W2     = (const float*)d_in[4];
  const float* b2     = (const float*)d_in[5];
  const float* Wf     = (const float*)d_in[6];
  // d_in[7] = bf : softmax shift-invariant, provably unused.

  float* out   = (float*)d_out;
  float* att   = out;              // [64][2048]
  float* alpha = out + BB*D2c;     // [64][196]

  char*   ws     = (char*)d_ws;
  ushort* w2t    = (ushort*)ws;                              // 2 MiB
  float*  enc1   = (float*)(ws + 2*1024*1024);               // 128 KiB
  float*  scores = (float*)(ws + 2*1024*1024 + 131072);      // 50 KiB

  hipMemsetAsync(scores, 0, MM*sizeof(float), stream);
  w2t_kernel<<<dim3(32, 8), 256, 0, stream>>>(W2, w2t);
  enc1_kernel<<<dim3(BB, 4), 128, 0, stream>>>(input1, W1, b1, enc1);
  score_gemm<<<dim3(4, 196), 256, 0, stream>>>(input2, w2t, b2, Wf, enc1, scores);
  softmax_kernel<<<dim3(BB), 64, 0, stream>>>(scores, alpha);
  att_kernel<<<dim3(8, BB), 256, 0, stream>>>(input2, alpha, att);
}

// Round 3
// 112.817 us; speedup vs baseline: 1.4490x; 1.3134x over previous
//
#include <hip/hip_runtime.h>
#include <hip/hip_bf16.h>
#include <stdint.h>

#define BB 64
#define NN 196
#define D1c 512
#define D2c 2048
#define HHc 512
#define MM (BB*NN)   // 12544

typedef __attribute__((ext_vector_type(8))) short bf16x8;
typedef __attribute__((ext_vector_type(4))) float f32x4;

__device__ inline ushort f2bf(float f){
  uint32_t u = __float_as_uint(f);
  u += 0x7fff + ((u >> 16) & 1);   // RNE
  return (ushort)(u >> 16);
}
__device__ inline uint32_t pack2(float a, float b){
  return (uint32_t)f2bf(a) | ((uint32_t)f2bf(b) << 16);
}

// ---- W2 [2048][512] f32  ->  w2t [512][2048] bf16 (transposed) ----
__global__ __launch_bounds__(256) void w2t_kernel(const float* __restrict__ W2,
                                                  ushort* __restrict__ w2t){
  __shared__ float tile[64][65];
  const int kt = blockIdx.x;           // 32 tiles of 64 k
  const int ht = blockIdx.y;           // 8 tiles of 64 h
  const int t = threadIdx.x;
  const int tr = t >> 4;               // 0..15
  const int tc = (t & 15) * 4;         // 0..60
  #pragma unroll
  for (int p = 0; p < 4; ++p){
    int k = p*16 + tr;
    float4 v = *(const float4*)(W2 + (size_t)(kt*64 + k)*HHc + ht*64 + tc);
    tile[k][tc] = v.x; tile[k][tc+1] = v.y; tile[k][tc+2] = v.z; tile[k][tc+3] = v.w;
  }
  __syncthreads();
  #pragma unroll
  for (int p = 0; p < 4; ++p){
    int h = p*16 + tr;
    ushort4 o;
    o.x = f2bf(tile[tc  ][h]);
    o.y = f2bf(tile[tc+1][h]);
    o.z = f2bf(tile[tc+2][h]);
    o.w = f2bf(tile[tc+3][h]);
    *(ushort4*)(w2t + (size_t)(ht*64 + h)*D2c + kt*64 + tc) = o;
  }
}

// ---- enc1 = input1 @ W1 + b1   [64][512] f32 ----
__global__ __launch_bounds__(128) void enc1_kernel(const float* __restrict__ in1,
                                                   const float* __restrict__ W1,
                                                   const float* __restrict__ b1,
                                                   float* __restrict__ enc1){
  __shared__ float s1[D1c];
  const int b = blockIdx.x;
  const int ht = blockIdx.y;
  const int t = threadIdx.x;
  ((float4*)s1)[t] = ((const float4*)(in1 + (size_t)b*D1c))[t];
  __syncthreads();
  const int h = ht*128 + t;
  float acc = b1[h];
  #pragma unroll 8
  for (int d = 0; d < D1c; ++d)
    acc += s1[d] * W1[(size_t)d*HHc + h];
  enc1[b*HHc + h] = acc;
}

// ---- fused scores GEMM:  scores[m] += sum_h relu(A@W2 + b2 + enc1) * Wf ----
// tile: 64m x 256h (h-split 2), BK=64, 4 waves each 64x64 (4x4 frags).
// counted-vmcnt pipeline, raw barriers, dbuf LDS 80KB -> 2 blocks/CU.
__global__ __launch_bounds__(256,2) void score_gemm(
    const float*  __restrict__ in2,
    const ushort* __restrict__ w2t,     // [512][2048] bf16
    const float*  __restrict__ b2,
    const float*  __restrict__ wf,
    const float*  __restrict__ enc1,    // [64][512]
    float*        __restrict__ scores)  // [12544], pre-zeroed
{
  __shared__ ushort As[2][64*64];    // [row][k], 16B-chunk XOR swizzle c^=(row&7)
  __shared__ ushort Bs[2][256*64];   // [h][k], same swizzle

  const int t = threadIdx.x;
  // bijective XCD swizzle: 392 blocks = 8 XCD x 49; h-pairs of one m-panel adjacent
  const int p  = blockIdx.x;
  const int lg = (p & 7) * 49 + (p >> 3);
  const int h0 = (lg & 1) * 256;
  const int m0 = (lg >> 1) * 64;

  const int wave = t >> 6, lane = t & 63;
  const int l15 = lane & 15, l4 = lane >> 4;

  // A staging: thread -> row t>>2, k-quarter (t&3)*16 (4 consecutive float4)
  const int arow = t >> 2;
  const int aq   = t & 3;
  const float* aBase = in2 + (size_t)(m0 + arow)*D2c + aq*16;
  const int ac0 = ((aq*2    ) ^ (arow & 7)) << 3;
  const int ac1 = ((aq*2 + 1) ^ (arow & 7)) << 3;

  // B glds: 8 per wave, each fills 8 rows x 128B; pre-swizzled global source
  const int bl_r = lane >> 3;
  const int bl_c = (lane & 7) ^ bl_r;

  float b2v[4], wfv[4];
  #pragma unroll
  for (int hf = 0; hf < 4; ++hf){
    int hc = h0 + wave*64 + hf*16 + l15;
    b2v[hf] = b2[hc]; wfv[hf] = wf[hc];
  }

  f32x4 acc[4][4];
  #pragma unroll
  for (int i = 0; i < 4; ++i)
    #pragma unroll
    for (int j = 0; j < 4; ++j) acc[i][j] = (f32x4)0.f;

  float4 aReg[4];

#define A_LOAD(kt)                                                           \
  { _Pragma("unroll")                                                        \
    for (int j = 0; j < 4; ++j)                                              \
      aReg[j] = *(const float4*)(aBase + (kt)*64 + j*4); }

#define A_WRITE(buf)                                                         \
  { uint4 w0, w1;                                                            \
    w0.x = pack2(aReg[0].x, aReg[0].y); w0.y = pack2(aReg[0].z, aReg[0].w);  \
    w0.z = pack2(aReg[1].x, aReg[1].y); w0.w = pack2(aReg[1].z, aReg[1].w);  \
    w1.x = pack2(aReg[2].x, aReg[2].y); w1.y = pack2(aReg[2].z, aReg[2].w);  \
    w1.z = pack2(aReg[3].x, aReg[3].y); w1.w = pack2(aReg[3].z, aReg[3].w);  \
    *(uint4*)(As[buf] + arow*64 + ac0) = w0;                                 \
    *(uint4*)(As[buf] + arow*64 + ac1) = w1; }

#define B_GLDS(kt, buf)                                                      \
  { _Pragma("unroll")                                                        \
    for (int i = 0; i < 8; ++i){                                             \
      const ushort* src = w2t + (size_t)(h0 + wave*64 + i*8 + bl_r)*D2c      \
                          + (kt)*64 + bl_c*8;                                \
      __builtin_amdgcn_global_load_lds(                                      \
          (const __attribute__((address_space(1))) uint32_t*)src,            \
          (__attribute__((address_space(3))) uint32_t*)(Bs[buf] + (wave*64 + i*8)*64), \
          16, 0, 0); } }

#define COMPUTE(buf)                                                         \
  { _Pragma("unroll")                                                        \
    for (int kk = 0; kk < 2; ++kk){                                          \
      bf16x8 af[4], bfr[4];                                                  \
      _Pragma("unroll")                                                      \
      for (int mf = 0; mf < 4; ++mf){                                        \
        int r = mf*16 + l15, c = kk*4 + l4;                                  \
        af[mf] = *(const bf16x8*)(As[buf] + r*64 + ((c ^ (r & 7)) << 3)); }  \
      _Pragma("unroll")                                                      \
      for (int hf = 0; hf < 4; ++hf){                                        \
        int r = wave*64 + hf*16 + l15, c = kk*4 + l4;                        \
        bfr[hf] = *(const bf16x8*)(Bs[buf] + r*64 + ((c ^ (r & 7)) << 3)); } \
      _Pragma("unroll")                                                      \
      for (int mf = 0; mf < 4; ++mf)                                         \
        _Pragma("unroll")                                                    \
        for (int hf = 0; hf < 4; ++hf)                                       \
          acc[mf][hf] = __builtin_amdgcn_mfma_f32_16x16x32_bf16(             \
              af[mf], bfr[hf], acc[mf][hf], 0, 0, 0); } }

#define SB0() __builtin_amdgcn_sched_barrier(0)
#define BAR() { SB0(); __builtin_amdgcn_s_barrier(); SB0(); }

  // prologue: stage kt=0 (A via regs, B via glds)
  A_LOAD(0);
  SB0();
  B_GLDS(0, 0);                              // out: A0(4) oldest, glds0(8)
  asm volatile("s_waitcnt vmcnt(8)" ::: "memory");   // A0 in regs
  SB0();
  A_WRITE(0);
  asm volatile("s_waitcnt lgkmcnt(0)" ::: "memory");
  BAR();                                     // As0 ready; glds0 still in flight

  for (int kt = 0; kt < 31; ++kt){
    const int cur = kt & 1;
    A_LOAD(kt + 1);                          // 4 vmem (after glds(kt) in order)
    SB0();
    B_GLDS(kt + 1, cur ^ 1);                 // 8 vmem; out = 8 + 4 + 8 = 20
    asm volatile("s_waitcnt vmcnt(12)" ::: "memory");  // glds(kt) landed
    BAR();                                   // all waves: Bs[cur] complete
    COMPUTE(cur);
    asm volatile("s_waitcnt vmcnt(8)" ::: "memory");   // A(kt+1) in regs
    SB0();
    A_WRITE(cur ^ 1);
    asm volatile("s_waitcnt lgkmcnt(0)" ::: "memory");
    BAR();                                   // out on exit: glds(kt+1) = 8
  }
  asm volatile("s_waitcnt vmcnt(0)" ::: "memory");     // glds(31) landed
  BAR();
  COMPUTE(1);

  // epilogue: relu + Wf partial over this wave's 64 h, atomic into scores
  #pragma unroll
  for (int mf = 0; mf < 4; ++mf){
    #pragma unroll
    for (int r = 0; r < 4; ++r){
      int m = m0 + mf*16 + l4*4 + r;   // C/D: row=(lane>>4)*4+reg, col=lane&15
      int b = m / NN;
      const float* e1 = enc1 + (size_t)b*HHc + h0 + wave*64 + l15;
      float s = 0.f;
      #pragma unroll
      for (int hf = 0; hf < 4; ++hf){
        float v = acc[mf][hf][r] + b2v[hf] + e1[hf*16];
        s += fmaxf(v, 0.f) * wfv[hf];
      }
      s += __shfl_xor(s, 1); s += __shfl_xor(s, 2);
      s += __shfl_xor(s, 4); s += __shfl_xor(s, 8);
      if (l15 == 0) atomicAdd(&scores[m], s);
    }
  }
#undef A_LOAD
#undef A_WRITE
#undef B_GLDS
#undef COMPUTE
#undef SB0
#undef BAR
}

// ---- softmax over N=196 per batch ----
__global__ __launch_bounds__(64) void softmax_kernel(const float* __restrict__ scores,
                                                     float* __restrict__ alpha){
  const int b = blockIdx.x, t = threadIdx.x;
  const float* s = scores + b*NN;
  float x[4]; float mx = -1e30f;
  #pragma unroll
  for (int i = 0; i < 4; ++i){
    int n = t + i*64;
    x[i] = (n < NN) ? s[n] : -1e30f;
    mx = fmaxf(mx, x[i]);
  }
  #pragma unroll
  for (int o = 1; o < 64; o <<= 1) mx = fmaxf(mx, __shfl_xor(mx, o));
  float sum = 0.f;
  #pragma unroll
  for (int i = 0; i < 4; ++i){
    int n = t + i*64;
    float e = (n < NN) ? __expf(x[i] - mx) : 0.f;
    x[i] = e; sum += e;
  }
  #pragma unroll
  for (int o = 1; o < 64; o <<= 1) sum += __shfl_xor(sum, o);
  float inv = 1.f / sum;
  #pragma unroll
  for (int i = 0; i < 4; ++i){
    int n = t + i*64;
    if (n < NN) alpha[b*NN + n] = x[i] * inv;
  }
}

// ---- att[b,d] = sum_n input2[b,n,d] * alpha[b,n] ----
__global__ __launch_bounds__(256) void att_kernel(const float* __restrict__ in2,
                                                  const float* __restrict__ alpha,
                                                  float* __restrict__ att){
  __shared__ float sal[NN];
  const int b = blockIdx.y;
  const int t = threadIdx.x;
  if (t < NN) sal[t] = alpha[b*NN + t];
  __syncthreads();
  const int d = blockIdx.x*256 + t;
  const float* src = in2 + (size_t)b*NN*D2c + d;
  float acc = 0.f;
  #pragma unroll 7
  for (int n = 0; n < NN; ++n)
    acc += src[(size_t)n*D2c] * sal[n];
  att[(size_t)b*D2c + d] = acc;
}

extern "C" void kernel_launch(void* const* d_in, const int* in_sizes, int n_in,
                              void* d_out, int out_size, void* d_ws, size_t ws_size,
                              hipStream_t stream){
  (void)in_sizes; (void)n_in; (void)out_size; (void)ws_size;
  const float* input1 = (const float*)d_in[0];
  const float* input2 = (const float*)d_in[1];
  const float* W1     = (const float*)d_in[2];
  const float* b1     = (const float*)d_in[3];
  const float* W2     = (const float*)d_in[4];
  const float* b2     = (const float*)d_in[5];
  const float* Wf     = (const float*)d_in[6];
  // d_in[7] = bf : softmax shift-invariant, provably unused.

  float* out   = (float*)d_out;
  float* att   = out;              // [64][2048]
  float* alpha = out + BB*D2c;     // [64][196]

  char*   ws     = (char*)d_ws;
  ushort* w2t    = (ushort*)ws;                              // 2 MiB
  float*  enc1   = (float*)(ws + 2*1024*1024);               // 128 KiB
  float*  scores = (float*)(ws + 2*1024*1024 + 131072);      // 50 KiB

  hipMemsetAsync(scores, 0, MM*sizeof(float), stream);
  w2t_kernel<<<dim3(32, 8), 256, 0, stream>>>(W2, w2t);
  enc1_kernel<<<dim3(BB, 4), 128, 0, stream>>>(input1, W1, b1, enc1);
  score_gemm<<<dim3(392), 256, 0, stream>>>(input2, w2t, b2, Wf, enc1, scores);
  softmax_kernel<<<dim3(BB), 64, 0, stream>>>(scores, alpha);
  att_kernel<<<dim3(8, BB), 256, 0, stream>>>(input2, alpha, att);
}

// Round 4
// 105.266 us; speedup vs baseline: 1.5530x; 1.0717x over previous
//
#include <hip/hip_runtime.h>
#include <hip/hip_bf16.h>
#include <stdint.h>

#define BB 64
#define NN 196
#define D1c 512
#define D2c 2048
#define HHc 512
#define MM (BB*NN)   // 12544

typedef __attribute__((ext_vector_type(8))) short bf16x8;
typedef __attribute__((ext_vector_type(4))) float f32x4;

__device__ inline ushort f2bf(float f){
  uint32_t u = __float_as_uint(f);
  u += 0x7fff + ((u >> 16) & 1);   // RNE
  return (ushort)(u >> 16);
}
__device__ inline uint32_t pack2(float a, float b){
  return (uint32_t)f2bf(a) | ((uint32_t)f2bf(b) << 16);
}

// ---- W2 [2048][512] f32 -> w2t in MFMA-fragment order (bf16) ----
// frag addr(h,k) = (h>>4)*32768 + (k>>6)*1024 + ((k>>5)&1)*512
//                + ((k>>3)&3)*128 + (h&15)*8 + (k&7)
// so B-frag(hf,kk) for a wave is ONE coalesced 16B/lane load.
__global__ __launch_bounds__(256) void w2t_kernel(const float* __restrict__ W2,
                                                  ushort* __restrict__ w2t){
  __shared__ float tile[64][65];
  const int ktb = blockIdx.x;          // 32 tiles of 64 k
  const int ht  = blockIdx.y;          // 8 tiles of 64 h
  const int t = threadIdx.x;
  const int tr = t >> 4;               // 0..15
  const int tc = (t & 15) * 4;         // 0..60
  #pragma unroll
  for (int p = 0; p < 4; ++p){
    int k = p*16 + tr;
    float4 v = *(const float4*)(W2 + (size_t)(ktb*64 + k)*HHc + ht*64 + tc);
    tile[k][tc] = v.x; tile[k][tc+1] = v.y; tile[k][tc+2] = v.z; tile[k][tc+3] = v.w;
  }
  __syncthreads();
  #pragma unroll
  for (int pp = 0; pp < 4; ++pp){
    int hl = pp*16 + tr;               // local h
    ushort4 o;
    o.x = f2bf(tile[tc  ][hl]);
    o.y = f2bf(tile[tc+1][hl]);
    o.z = f2bf(tile[tc+2][hl]);
    o.w = f2bf(tile[tc+3][hl]);
    size_t addr = (size_t)(ht*4 + pp)*32768 + (size_t)ktb*1024
                + (size_t)((tc>>5)&1)*512 + (size_t)((tc>>3)&3)*128
                + (size_t)tr*8 + (tc & 4);
    *(ushort4*)(w2t + addr) = o;
  }
}

// ---- enc1 = input1 @ W1 + b1   [64][512] f32 ----
__global__ __launch_bounds__(128) void enc1_kernel(const float* __restrict__ in1,
                                                   const float* __restrict__ W1,
                                                   const float* __restrict__ b1,
                                                   float* __restrict__ enc1){
  __shared__ float s1[D1c];
  const int b = blockIdx.x;
  const int ht = blockIdx.y;
  const int t = threadIdx.x;
  ((float4*)s1)[t] = ((const float4*)(in1 + (size_t)b*D1c))[t];
  __syncthreads();
  const int h = ht*128 + t;
  float acc = b1[h];
  #pragma unroll 8
  for (int d = 0; d < D1c; ++d)
    acc += s1[d] * W1[(size_t)d*HHc + h];
  enc1[b*HHc + h] = acc;
}

// ---- fused scores GEMM:  scores[m] += sum_h relu(A@W2 + b2 + enc1) * Wf ----
// tile: 64m x 256h, BK=64, 4 waves each 64x64.
// A: LDS-staged (reg convert, XOR swizzle), double-buffered (16KB total).
// B: NO LDS — fragment-ordered w2t, coalesced loads into double-buffered regs.
__global__ __launch_bounds__(256) void score_gemm(
    const float*  __restrict__ in2,
    const ushort* __restrict__ w2t,     // fragment-ordered bf16
    const float*  __restrict__ b2,
    const float*  __restrict__ wf,
    const float*  __restrict__ enc1,    // [64][512]
    float*        __restrict__ scores)  // [12544], pre-zeroed
{
  __shared__ ushort As[2][64*64];    // [row][k], 16B-chunk XOR swizzle c^=(row&7)

  const int t = threadIdx.x;
  // bijective XCD swizzle: 392 blocks = 8 XCD x 49; h-pair of one m-panel adjacent
  const int p  = blockIdx.x;
  const int lg = (p & 7) * 49 + (p >> 3);
  const int h0 = (lg & 1) * 256;
  const int m0 = (lg >> 1) * 64;

  const int wave = t >> 6, lane = t & 63;
  const int l15 = lane & 15, l4 = lane >> 4;

  // A staging: thread -> row t>>2, k-quarter (t&3)*16 (4 consecutive float4)
  const int arow = t >> 2;
  const int aq   = t & 3;
  const float* aBase = in2 + (size_t)(m0 + arow)*D2c + aq*16;
  const int ac0 = ((aq*2    ) ^ (arow & 7)) << 3;
  const int ac1 = ((aq*2 + 1) ^ (arow & 7)) << 3;

  // B fragment base for this wave/lane
  const ushort* bBase = w2t + (size_t)h0*2048 + (size_t)wave*131072 + lane*8;

  float b2v[4], wfv[4];
  #pragma unroll
  for (int hf = 0; hf < 4; ++hf){
    int hc = h0 + wave*64 + hf*16 + l15;
    b2v[hf] = b2[hc]; wfv[hf] = wf[hc];
  }

  f32x4 acc[4][4];
  #pragma unroll
  for (int i = 0; i < 4; ++i)
    #pragma unroll
    for (int j = 0; j < 4; ++j) acc[i][j] = (f32x4)0.f;

  float4 aReg[4];
  bf16x8 bA[8], bB[8];

#define A_LOAD(kt)                                                           \
  { _Pragma("unroll")                                                        \
    for (int j = 0; j < 4; ++j)                                              \
      aReg[j] = *(const float4*)(aBase + (kt)*64 + j*4); }

#define B_LOAD(kt, B)                                                        \
  { _Pragma("unroll")                                                        \
    for (int f = 0; f < 8; ++f)                                              \
      B[f] = *(const bf16x8*)(bBase + (f>>1)*32768 + (kt)*1024 + (f&1)*512); }

#define A_WRITE(buf)                                                         \
  { uint4 w0, w1;                                                            \
    w0.x = pack2(aReg[0].x, aReg[0].y); w0.y = pack2(aReg[0].z, aReg[0].w);  \
    w0.z = pack2(aReg[1].x, aReg[1].y); w0.w = pack2(aReg[1].z, aReg[1].w);  \
    w1.x = pack2(aReg[2].x, aReg[2].y); w1.y = pack2(aReg[2].z, aReg[2].w);  \
    w1.z = pack2(aReg[3].x, aReg[3].y); w1.w = pack2(aReg[3].z, aReg[3].w);  \
    *(uint4*)(As[buf] + arow*64 + ac0) = w0;                                 \
    *(uint4*)(As[buf] + arow*64 + ac1) = w1; }

#define COMPUTE(buf, B)                                                      \
  { _Pragma("unroll")                                                        \
    for (int kk = 0; kk < 2; ++kk){                                          \
      bf16x8 af[4];                                                          \
      _Pragma("unroll")                                                      \
      for (int mf = 0; mf < 4; ++mf){                                        \
        int r = mf*16 + l15, c = kk*4 + l4;                                  \
        af[mf] = *(const bf16x8*)(As[buf] + r*64 + ((c ^ (r & 7)) << 3)); }  \
      _Pragma("unroll")                                                      \
      for (int mf = 0; mf < 4; ++mf)                                         \
        _Pragma("unroll")                                                    \
        for (int hf = 0; hf < 4; ++hf)                                       \
          acc[mf][hf] = __builtin_amdgcn_mfma_f32_16x16x32_bf16(             \
              af[mf], B[hf*2+kk], acc[mf][hf], 0, 0, 0); } }

#define LGKM0() asm volatile("s_waitcnt lgkmcnt(0)" ::: "memory")
#define SB0()   __builtin_amdgcn_sched_barrier(0)
#define BAR()   { SB0(); __builtin_amdgcn_s_barrier(); SB0(); }

  // prologue: stage kt=0
  A_LOAD(0);
  B_LOAD(0, bA);
  A_WRITE(0);                // compiler waits vmcnt for aReg
  LGKM0();
  BAR();

  #pragma unroll 1
  for (int kt = 0; kt < 30; kt += 2){
    // even step: compute As[0]/bA, prefetch kt+1 into As[1]/bB
    A_LOAD(kt + 1);
    B_LOAD(kt + 1, bB);
    COMPUTE(0, bA);
    A_WRITE(1);
    LGKM0();
    BAR();
    // odd step: compute As[1]/bB, prefetch kt+2 into As[0]/bA
    A_LOAD(kt + 2);
    B_LOAD(kt + 2, bA);
    COMPUTE(1, bB);
    A_WRITE(0);
    LGKM0();
    BAR();
  }
  // kt = 30
  A_LOAD(31);
  B_LOAD(31, bB);
  COMPUTE(0, bA);
  A_WRITE(1);
  LGKM0();
  BAR();
  // kt = 31
  COMPUTE(1, bB);

  // epilogue: relu + Wf partial over this wave's 64 h, atomic into scores
  #pragma unroll
  for (int mf = 0; mf < 4; ++mf){
    #pragma unroll
    for (int r = 0; r < 4; ++r){
      int m = m0 + mf*16 + l4*4 + r;   // C/D: row=(lane>>4)*4+reg, col=lane&15
      int b = m / NN;
      const float* e1 = enc1 + (size_t)b*HHc + h0 + wave*64 + l15;
      float s = 0.f;
      #pragma unroll
      for (int hf = 0; hf < 4; ++hf){
        float v = acc[mf][hf][r] + b2v[hf] + e1[hf*16];
        s += fmaxf(v, 0.f) * wfv[hf];
      }
      s += __shfl_xor(s, 1); s += __shfl_xor(s, 2);
      s += __shfl_xor(s, 4); s += __shfl_xor(s, 8);
      if (l15 == 0) atomicAdd(&scores[m], s);
    }
  }
#undef A_LOAD
#undef B_LOAD
#undef A_WRITE
#undef COMPUTE
#undef LGKM0
#undef SB0
#undef BAR
}

// ---- softmax over N=196 per batch ----
__global__ __launch_bounds__(64) void softmax_kernel(const float* __restrict__ scores,
                                                     float* __restrict__ alpha){
  const int b = blockIdx.x, t = threadIdx.x;
  const float* s = scores + b*NN;
  float x[4]; float mx = -1e30f;
  #pragma unroll
  for (int i = 0; i < 4; ++i){
    int n = t + i*64;
    x[i] = (n < NN) ? s[n] : -1e30f;
    mx = fmaxf(mx, x[i]);
  }
  #pragma unroll
  for (int o = 1; o < 64; o <<= 1) mx = fmaxf(mx, __shfl_xor(mx, o));
  float sum = 0.f;
  #pragma unroll
  for (int i = 0; i < 4; ++i){
    int n = t + i*64;
    float e = (n < NN) ? __expf(x[i] - mx) : 0.f;
    x[i] = e; sum += e;
  }
  #pragma unroll
  for (int o = 1; o < 64; o <<= 1) sum += __shfl_xor(sum, o);
  float inv = 1.f / sum;
  #pragma unroll
  for (int i = 0; i < 4; ++i){
    int n = t + i*64;
    if (n < NN) alpha[b*NN + n] = x[i] * inv;
  }
}

// ---- att[b,d] = sum_n input2[b,n,d] * alpha[b,n] ----
__global__ __launch_bounds__(256) void att_kernel(const float* __restrict__ in2,
                                                  const float* __restrict__ alpha,
                                                  float* __restrict__ att){
  __shared__ float sal[NN];
  const int b = blockIdx.y;
  const int t = threadIdx.x;
  if (t < NN) sal[t] = alpha[b*NN + t];
  __syncthreads();
  const int d = blockIdx.x*256 + t;
  const float* src = in2 + (size_t)b*NN*D2c + d;
  float acc = 0.f;
  #pragma unroll 7
  for (int n = 0; n < NN; ++n)
    acc += src[(size_t)n*D2c] * sal[n];
  att[(size_t)b*D2c + d] = acc;
}

extern "C" void kernel_launch(void* const* d_in, const int* in_sizes, int n_in,
                              void* d_out, int out_size, void* d_ws, size_t ws_size,
                              hipStream_t stream){
  (void)in_sizes; (void)n_in; (void)out_size; (void)ws_size;
  const float* input1 = (const float*)d_in[0];
  const float* input2 = (const float*)d_in[1];
  const float* W1     = (const float*)d_in[2];
  const float* b1     = (const float*)d_in[3];
  const float* W2     = (const float*)d_in[4];
  const float* b2     = (const float*)d_in[5];
  const float* Wf     = (const float*)d_in[6];
  // d_in[7] = bf : softmax shift-invariant, provably unused.

  float* out   = (float*)d_out;
  float* att   = out;              // [64][2048]
  float* alpha = out + BB*D2c;     // [64][196]

  char*   ws     = (char*)d_ws;
  ushort* w2t    = (ushort*)ws;                              // 2 MiB (frag order)
  float*  enc1   = (float*)(ws + 2*1024*1024);               // 128 KiB
  float*  scores = (float*)(ws + 2*1024*1024 + 131072);      // 50 KiB

  hipMemsetAsync(scores, 0, MM*sizeof(float), stream);
  w2t_kernel<<<dim3(32, 8), 256, 0, stream>>>(W2, w2t);
  enc1_kernel<<<dim3(BB, 4), 128, 0, stream>>>(input1, W1, b1, enc1);
  score_gemm<<<dim3(392), 256, 0, stream>>>(input2, w2t, b2, Wf, enc1, scores);
  softmax_kernel<<<dim3(BB), 64, 0, stream>>>(scores, alpha);
  att_kernel<<<dim3(8, BB), 256, 0, stream>>>(input2, alpha, att);
}